// Round 5
// baseline (119.339 us; speedup 1.0000x reference)
//
#include <hip/hip_runtime.h>
#include <cstdint>

#define BATCH 64
#define NPIX 65536
#define TOPK 16384
#define NB 256
#define SEGS 16       // k1 blocks per batch (8 pairs/thread, 4096 px/block)
#define WLO 186       // candidate window low bin (threshold bin ~192)
#define WHI 198       // candidate window high bin
#define NWBIN (WHI - WLO + 1)
#define CAPB 320      // per-block window-candidate slots (expect ~208, sigma~14)
#define NSLOT (SEGS * CAPB)   // 5120
#define FCAP 1024     // threshold-bin rank buffer (expect ~256, sigma~16)
#define WHSTRIDE 16   // padded per-block histogram stride (13 used)
#define ITERS 8       // pairs per thread

// ---- 256-thread triple block reduce (k1): one barrier set for 3 values ----
__device__ __forceinline__ void block_reduce3(
    float a, float b, float c, float* o0, float* o1, float* o2)
{
    __shared__ float w[12];
    __syncthreads();
    #pragma unroll
    for (int off = 32; off > 0; off >>= 1) {
        a += __shfl_down(a, off, 64);
        b += __shfl_down(b, off, 64);
        c += __shfl_down(c, off, 64);
    }
    int wid = threadIdx.x >> 6;
    if ((threadIdx.x & 63) == 0) { w[wid] = a; w[wid + 4] = b; w[wid + 8] = c; }
    __syncthreads();
    *o0 = w[0] + w[1] + w[2] + w[3];
    *o1 = w[4] + w[5] + w[6] + w[7];
    *o2 = w[8] + w[9] + w[10] + w[11];
}

// ---- 1024-thread block reduce (k4) ----
__device__ __forceinline__ float block_reduce1k(float acc) {
    __shared__ float w[16];
    __syncthreads();
    #pragma unroll
    for (int off = 32; off > 0; off >>= 1) acc += __shfl_down(acc, off, 64);
    if ((threadIdx.x & 63) == 0) w[threadIdx.x >> 6] = acc;
    __syncthreads();
    float s = 0.f;
    #pragma unroll
    for (int i = 0; i < 16; ++i) s += w[i];
    return s;
}

// p = softmax(a0,a1)[0] = sigmoid(d), d = a0-a1.
// lp = log p = min(d,0)-t ; llp = log(1-p) = -max(d,0)-t, t = log(1+exp(-|d|)).
__device__ __forceinline__ void bce_from_d(float d, float& lp, float& llp) {
    float t = __logf(1.f + __expf(-fabsf(d)));
    lp  = fmaxf(fminf(d, 0.f) - t, -100.f);
    llp = fmaxf(-fmaxf(d, 0.f) - t, -100.f);
}

__device__ __forceinline__ int vkey(float v) {
    return (int)fminf(v * 256.0f, 255.0f);   // monotone bucket map, v in [0,1)
}

// Wave-ballot compaction: one leader LDS atomic per 64-lane check instead of
// a serialized per-lane atomic chain. Slot order is arbitrary (k4 ranks by
// value/index); ccount total (overflow detection) is exact.
__device__ __forceinline__ void stage_candidate(
    bool inwin, float v, uint32_t pix, float diff, int lane,
    uint32_t* ccount, uint32_t* bvb, uint32_t* bvi, uint32_t* bvd)
{
    unsigned long long m = __ballot(inwin);
    if (m == 0ull) return;                       // wave-uniform skip
    uint32_t cnt = (uint32_t)__popcll(m);
    int leader = (int)__builtin_ctzll(m);
    uint32_t base = 0u;
    if (lane == leader) base = atomicAdd(ccount, cnt);
    base = (uint32_t)__shfl((int)base, leader, 64);
    if (inwin) {
        uint32_t p = base + (uint32_t)__popcll(m & ((1ull << lane) - 1ull));
        if (p < CAPB) {
            bvb[p] = __float_as_uint(v);
            bvi[p] = pix;
            bvd[p] = __float_as_uint(diff);
        }
    }
}

// ---------------------------------------------------------------------------
// K1: 8 pairs/thread (1024 blocks, half of round-4's 2048) so the per-block
// tail (histogram+prefix+scatter+publish+reduce, ~6 barriers) is paid half
// as often; triple-reduce fuses 3 block_reduces into one. Ballot staging +
// full depth-8 preload (~320B/thread in flight; launch_bounds(256,4) gives
// 16 waves/CU, ample for the mixed L3/HBM stream). Bucketed publish + per-bin
// diff sums as in round 4. Block 0 zeroes out[0]. No device fences.
// ---------------------------------------------------------------------------
__global__ __launch_bounds__(256, 4) void k1_pass(
    const float4* __restrict__ sc, const float4* __restrict__ gn,
    const float2* __restrict__ tokp,
    float* __restrict__ pk1, float* __restrict__ psel, float* __restrict__ phi,
    uint32_t* __restrict__ gcc,
    uint32_t* __restrict__ cvb, uint32_t* __restrict__ cvi,
    uint32_t* __restrict__ cvd, uint32_t* __restrict__ whist,
    float* __restrict__ wdsumg,
    float* __restrict__ out)
{
    __shared__ uint32_t bvb[CAPB], bvi[CAPB], bvd[CAPB];    // staging order
    __shared__ uint32_t qvb[CAPB], qvi[CAPB], qvd[CAPB];    // bucketed order
    __shared__ uint32_t sh_wh[NWBIN], sh_pref[NWBIN], sh_cur[NWBIN];
    __shared__ float    sh_wds[NWBIN];
    __shared__ uint32_t ccount;
    const int tid  = threadIdx.x;
    const int lane = tid & 63;
    for (int i = tid; i < CAPB; i += 256) { qvb[i] = 0u; qvi[i] = 0u; qvd[i] = 0u; }
    if (tid < NWBIN) { sh_wh[tid] = 0u; sh_cur[tid] = 0u; sh_wds[tid] = 0.f; }
    if (tid == 0) { ccount = 0u; if (blockIdx.x == 0) out[0] = 0.f; }
    __syncthreads();

    const int b   = blockIdx.x >> 4;
    const int seg = blockIdx.x & (SEGS - 1);
    const int pairbase = b * (NPIX / 2) + seg * (ITERS * 256);  // 2048 pairs/blk

    // ---- phase 1: issue ALL loads (static indexing -> registers) ----
    float4 S[ITERS], G[ITERS];
    float2 T[ITERS];
    #pragma unroll
    for (int it = 0; it < ITERS; ++it) {
        int j = pairbase + it * 256 + tid;
        S[it] = sc[j];
        G[it] = gn[j];
        T[it] = tokp[j];
    }

    // ---- phase 2: compute ----
    float acc = 0.f, asel = 0.f, chi = 0.f;
    #pragma unroll
    for (int it = 0; it < ITERS; ++it) {
        int px0 = (seg * (ITERS * 256) + it * 256 + tid) * 2;  // batch-local px
        {
            float d = (S[it].x + G[it].x) - (S[it].y + G[it].y);
            float lp, llp; bce_from_d(d, lp, llp);
            acc += llp;
            float diff = lp - llp;
            int k = vkey(T[it].x);
            bool hi = (k > WHI);
            asel += hi ? diff : 0.f;
            chi  += hi ? 1.f : 0.f;
            stage_candidate(!hi && (k >= WLO), T[it].x, (uint32_t)px0, diff,
                            lane, &ccount, bvb, bvi, bvd);
        }
        {
            float d = (S[it].z + G[it].z) - (S[it].w + G[it].w);
            float lp, llp; bce_from_d(d, lp, llp);
            acc += llp;
            float diff = lp - llp;
            int k = vkey(T[it].y);
            bool hi = (k > WHI);
            asel += hi ? diff : 0.f;
            chi  += hi ? 1.f : 0.f;
            stage_candidate(!hi && (k >= WLO), T[it].y, (uint32_t)(px0 + 1), diff,
                            lane, &ccount, bvb, bvi, bvd);
        }
    }
    __syncthreads();
    const uint32_t cc  = ccount;
    const uint32_t nsl = cc < CAPB ? cc : CAPB;
    // bin histogram over stored slots (~208 LDS atomics)
    for (uint32_t i = tid; i < nsl; i += 256) {
        int k = vkey(__uint_as_float(bvb[i]));
        atomicAdd(&sh_wh[k - WLO], 1u);
    }
    __syncthreads();
    // exclusive prefix over 13 bins (serial, trivial)
    if (tid == 0) {
        uint32_t run = 0;
        #pragma unroll
        for (int i = 0; i < NWBIN; ++i) { sh_pref[i] = run; run += sh_wh[i]; }
    }
    __syncthreads();
    // scatter slots into bucketed order + per-bin diff sums
    for (uint32_t i = tid; i < nsl; i += 256) {
        uint32_t vb = bvb[i];
        int bin = vkey(__uint_as_float(vb)) - WLO;
        uint32_t pos = sh_pref[bin] + atomicAdd(&sh_cur[bin], 1u);
        qvb[pos] = vb;
        qvi[pos] = bvi[i];
        qvd[pos] = bvd[i];
        atomicAdd(&sh_wds[bin], __uint_as_float(bvd[i]));
    }
    __syncthreads();
    // publish bucketed fixed-size block (unused slots are zero sentinels)
    const size_t cbase = (size_t)blockIdx.x * CAPB;
    for (int i = tid; i < CAPB; i += 256) {
        cvb[cbase + i] = qvb[i];
        cvi[cbase + i] = qvi[i];
        cvd[cbase + i] = qvd[i];
    }
    if (tid == 0) gcc[blockIdx.x] = cc;

    float t1, t2, t3;
    block_reduce3(acc, asel, chi, &t1, &t2, &t3);
    if (tid == 0) {
        pk1[blockIdx.x]  = t1;
        psel[blockIdx.x] = t2;
        phi[blockIdx.x]  = t3;
    }
    if (tid < NWBIN) {
        whist[(size_t)blockIdx.x * WHSTRIDE + tid]  = sh_wh[tid];
        wdsumg[(size_t)blockIdx.x * WHSTRIDE + tid] = sh_wds[tid];
    }
}

// ---------------------------------------------------------------------------
// K4 (skinny, SEGS=16): no slot walk. wc from whist; bins>sb from precomputed
// wdsum (<=256 float reads); ==sb bucket gathered via per-seg prefix offsets
// (~256 entries, 64-thread group per seg). Exact rank under (value desc,
// index asc) == lax.top_k tie order. Exact full-rescan fallback on any
// overflow (prob ~1e-10).
// ---------------------------------------------------------------------------
__global__ __launch_bounds__(1024) void k4_finalize(
    const uint32_t* __restrict__ cvb, const uint32_t* __restrict__ cvi,
    const uint32_t* __restrict__ cvd, const uint32_t* __restrict__ gcc,
    const float* __restrict__ pk1, const float* __restrict__ psel,
    const float* __restrict__ phi, const uint32_t* __restrict__ whist,
    const float* __restrict__ wdsumg,
    const float4* __restrict__ tok4,
    const float2* __restrict__ sc2, const float2* __restrict__ gn2,
    float* __restrict__ out)
{
    __shared__ uint32_t fvb[FCAP], fvi[FCAP];
    __shared__ float    fdf[FCAP];
    __shared__ uint32_t fh[NB];              // fallback histogram
    __shared__ uint32_t wc[NWBIN];
    __shared__ uint32_t segstart[SEGS], segcnt[SEGS];
    __shared__ uint32_t fcnt;
    __shared__ int      sh_sb, sh_ovf;
    __shared__ uint32_t sh_rem;

    const int b = blockIdx.x, tid = threadIdx.x;
    if (tid == 0) { fcnt = 0u; sh_sb = -1; sh_ovf = 0; sh_rem = 1u; }
    __syncthreads();

    // --- window counts from published per-block histograms (tiny) ---
    if (tid < SEGS && gcc[b * SEGS + tid] > CAPB) sh_ovf = 1;
    if (tid < NWBIN) {
        uint32_t u = 0;
        #pragma unroll
        for (int s = 0; s < SEGS; ++s)
            u += whist[(size_t)(b * SEGS + s) * WHSTRIDE + tid];
        wc[tid] = u;
    }
    float chl = (tid < SEGS) ? phi[b * SEGS + tid] : 0.f;
    float chf = block_reduce1k(chl);     // exact: integer-valued floats < 2^24
    if (tid == 0) {
        uint32_t cnt_hi = (uint32_t)(chf + 0.5f);
        if (cnt_hi >= TOPK) sh_ovf = 1;  // split bin above window
        else {
            uint32_t cum = cnt_hi;       // S[WHI+1]
            int found = -1; uint32_t rem = 1u;
            for (int jj = WHI; jj >= WLO; --jj) {
                uint32_t nc = cum + wc[jj - WLO];     // S[jj]
                if (nc >= TOPK) { found = jj; rem = TOPK - cum; break; }
                cum = nc;
            }
            if (found < 0) sh_ovf = 1;   // split bin below window
            else { sh_sb = found; sh_rem = rem; }
        }
    }
    __syncthreads();

    bool fast = (sh_ovf == 0);
    const int sb  = sh_sb;
    const int sbi = sb - WLO;
    float fac = (tid < SEGS) ? pk1[b * SEGS + tid] : 0.f;   // base llp

    if (fast) {
        if (tid < SEGS) fac += psel[b * SEGS + tid];        // key > WHI diffs
        // bins > sb: precomputed per-block diff sums (<=256 reads)
        if (tid < SEGS * WHSTRIDE) {
            int s = tid >> 4, bin = tid & 15;
            if (bin < NWBIN && bin > sbi)
                fac += wdsumg[(size_t)(b * SEGS + s) * WHSTRIDE + bin];
        }
        // per-seg offset of the ==sb bucket (prefix of seg's whist row)
        if (tid < SEGS) {
            uint32_t st = 0;
            for (int i = 0; i < sbi; ++i)
                st += whist[(size_t)(b * SEGS + tid) * WHSTRIDE + i];
            segstart[tid] = st;
            segcnt[tid]   = whist[(size_t)(b * SEGS + tid) * WHSTRIDE + sbi];
        }
        __syncthreads();
        // gather ==sb bucket entries (~256 total); 64-thread group per seg
        {
            int g = tid >> 6, l64 = tid & 63;
            uint32_t c = segcnt[g];
            size_t sbase = (size_t)(b * SEGS + g) * CAPB + segstart[g];
            for (uint32_t i = l64; i < c; i += 64) {
                uint32_t p = atomicAdd(&fcnt, 1u);
                if (p < FCAP) {
                    fvb[p] = cvb[sbase + i];
                    fvi[p] = cvi[sbase + i] & (NPIX - 1);
                    fdf[p] = __uint_as_float(cvd[sbase + i]);
                }
            }
        }
        __syncthreads();
        if (fcnt > FCAP) fast = false;   // uniform decision (shared value)
        if (fast) {
            const uint32_t cnt = fcnt, rem = sh_rem;
            for (uint32_t j = tid; j < cnt; j += 1024) {
                const uint32_t mb = fvb[j], mi = fvi[j];
                uint32_t rank = 0;
                for (uint32_t i = 0; i < cnt; ++i) {
                    uint32_t ob = fvb[i];
                    rank += (ob > mb) || (ob == mb && fvi[i] < mi);
                }
                if (rank < rem) fac += fdf[j];
            }
        }
    }

    if (!fast) {
        // ---- exact fallback: full per-batch recount + recompute ----
        fac = (tid < SEGS) ? pk1[b * SEGS + tid] : 0.f;     // reset to base
        for (int i = tid; i < NB; i += 1024) fh[i] = 0u;
        if (tid == 0) fcnt = 0u;
        __syncthreads();
        const float4* tbase = tok4 + (size_t)b * (NPIX / 4);
        for (int it = 0; it < NPIX / 4 / 1024; ++it) {
            float4 v = tbase[it * 1024 + tid];
            atomicAdd(&fh[vkey(v.x)], 1u);
            atomicAdd(&fh[vkey(v.y)], 1u);
            atomicAdd(&fh[vkey(v.z)], 1u);
            atomicAdd(&fh[vkey(v.w)], 1u);
        }
        __syncthreads();
        if (tid == 0) {
            uint32_t cum = 0; int bin = NB - 1;
            for (; bin > 0; --bin) {
                if (cum + fh[bin] >= TOPK) break;
                cum += fh[bin];
            }
            sh_sb = bin; sh_rem = TOPK - cum;
        }
        __syncthreads();
        const int sb2 = sh_sb; const uint32_t rem2 = sh_rem;
        for (int it = 0; it < NPIX / 4 / 1024; ++it) {
            int j = it * 1024 + tid;
            float4 v = tbase[j];
            int px = j * 4;
            float fv[4] = {v.x, v.y, v.z, v.w};
            #pragma unroll
            for (int q = 0; q < 4; ++q) {
                int k = vkey(fv[q]);
                if (k > sb2) {
                    size_t idx = (size_t)b * NPIX + (px + q);
                    float2 Sv = sc2[idx]; float2 Gv = gn2[idx];
                    float d = (Sv.x + Gv.x) - (Sv.y + Gv.y);
                    float lp, llp; bce_from_d(d, lp, llp);
                    fac += lp - llp;
                } else if (k == sb2) {
                    uint32_t p = atomicAdd(&fcnt, 1u);
                    if (p < FCAP) { fvb[p] = __float_as_uint(fv[q]); fvi[p] = (uint32_t)(px + q); }
                }
            }
        }
        __syncthreads();
        const uint32_t cnt2 = min(fcnt, (uint32_t)FCAP);
        for (uint32_t j = tid; j < cnt2; j += 1024) {
            const uint32_t mb = fvb[j], mi = fvi[j];
            uint32_t rank = 0;
            for (uint32_t i = 0; i < cnt2; ++i) {
                uint32_t ob = fvb[i];
                rank += (ob > mb) || (ob == mb && fvi[i] < mi);
            }
            if (rank < rem2) {
                size_t idx = (size_t)b * NPIX + (mi & (NPIX - 1));
                float2 Sv = sc2[idx]; float2 Gv = gn2[idx];
                float d = (Sv.x + Gv.x) - (Sv.y + Gv.y);
                float lp, llp; bce_from_d(d, lp, llp);
                fac += lp - llp;
            }
        }
    }

    float tot = block_reduce1k(fac);
    if (tid == 0) atomicAdd(out, -tot);   // 64 adds, out zeroed by k1
}

extern "C" void kernel_launch(void* const* d_in, const int* in_sizes, int n_in,
                              void* d_out, int out_size, void* d_ws, size_t ws_size,
                              hipStream_t stream) {
    const float* scores = (const float*)d_in[0];   // [B, N, 2]
    const float* smap   = (const float*)d_in[1];   // [B, N]
    const float* gumbel = (const float*)d_in[2];   // [B, N, 2]
    float* out = (float*)d_out;

    // workspace: every region fully written before read -> NO memset needed
    char* ws = (char*)d_ws;
    float*    pk1   = (float*)ws;    ws += (size_t)BATCH * SEGS * 4;            // 4KB
    float*    psel  = (float*)ws;    ws += (size_t)BATCH * SEGS * 4;            // 4KB
    float*    phi   = (float*)ws;    ws += (size_t)BATCH * SEGS * 4;            // 4KB
    uint32_t* gcc   = (uint32_t*)ws; ws += (size_t)BATCH * SEGS * 4;            // 4KB
    uint32_t* cvb   = (uint32_t*)ws; ws += (size_t)BATCH * NSLOT * 4;           // 1.31MB
    uint32_t* cvi   = (uint32_t*)ws; ws += (size_t)BATCH * NSLOT * 4;           // 1.31MB
    uint32_t* cvd   = (uint32_t*)ws; ws += (size_t)BATCH * NSLOT * 4;           // 1.31MB
    uint32_t* whist = (uint32_t*)ws; ws += (size_t)BATCH * SEGS * WHSTRIDE * 4; // 64KB
    float*    wdsum = (float*)ws;    ws += (size_t)BATCH * SEGS * WHSTRIDE * 4; // 64KB

    k1_pass<<<BATCH * SEGS, 256, 0, stream>>>(
        (const float4*)scores, (const float4*)gumbel, (const float2*)smap,
        pk1, psel, phi, gcc, cvb, cvi, cvd, whist, wdsum, out);

    k4_finalize<<<BATCH, 1024, 0, stream>>>(
        cvb, cvi, cvd, gcc, pk1, psel, phi, whist, wdsum,
        (const float4*)smap, (const float2*)scores, (const float2*)gumbel, out);
}

// Round 6
// 116.865 us; speedup vs baseline: 1.0212x; 1.0212x over previous
//
#include <hip/hip_runtime.h>
#include <cstdint>

#define BATCH 64
#define NPIX 65536
#define TOPK 16384
#define NB 256
#define SEGS 32       // k1 blocks per batch
#define WLO 186       // candidate window low bin (threshold bin ~192)
#define WHI 198       // candidate window high bin
#define NWBIN (WHI - WLO + 1)
#define CAPB 192      // per-block window-candidate slots (expect ~104, sigma~10)
#define NSLOT (SEGS * CAPB)   // 6144
#define FCAP 1024     // threshold-bin rank buffer (expect ~256, sigma~16)
#define WHSTRIDE 16   // padded per-block histogram stride (13 used)

// ---- 256-thread triple block reduce (k1): one barrier set for 3 values ----
__device__ __forceinline__ void block_reduce3(
    float a, float b, float c, float* o0, float* o1, float* o2)
{
    __shared__ float w[12];
    __syncthreads();
    #pragma unroll
    for (int off = 32; off > 0; off >>= 1) {
        a += __shfl_down(a, off, 64);
        b += __shfl_down(b, off, 64);
        c += __shfl_down(c, off, 64);
    }
    int wid = threadIdx.x >> 6;
    if ((threadIdx.x & 63) == 0) { w[wid] = a; w[wid + 4] = b; w[wid + 8] = c; }
    __syncthreads();
    *o0 = w[0] + w[1] + w[2] + w[3];
    *o1 = w[4] + w[5] + w[6] + w[7];
    *o2 = w[8] + w[9] + w[10] + w[11];
}

// ---- 1024-thread block reduce (k4) ----
__device__ __forceinline__ float block_reduce1k(float acc) {
    __shared__ float w[16];
    __syncthreads();
    #pragma unroll
    for (int off = 32; off > 0; off >>= 1) acc += __shfl_down(acc, off, 64);
    if ((threadIdx.x & 63) == 0) w[threadIdx.x >> 6] = acc;
    __syncthreads();
    float s = 0.f;
    #pragma unroll
    for (int i = 0; i < 16; ++i) s += w[i];
    return s;
}

// p = softmax(a0,a1)[0] = sigmoid(d), d = a0-a1.
// lp = log p = min(d,0)-t ; llp = log(1-p) = -max(d,0)-t, t = log(1+exp(-|d|)).
__device__ __forceinline__ void bce_from_d(float d, float& lp, float& llp) {
    float t = __logf(1.f + __expf(-fabsf(d)));
    lp  = fmaxf(fminf(d, 0.f) - t, -100.f);
    llp = fmaxf(-fmaxf(d, 0.f) - t, -100.f);
}

__device__ __forceinline__ int vkey(float v) {
    return (int)fminf(v * 256.0f, 255.0f);   // monotone bucket map, v in [0,1)
}

// Wave-ballot compaction: one leader LDS atomic per 64-lane check instead of
// a serialized per-lane atomic chain. Slot order is arbitrary (k4 ranks by
// value/index); ccount total (overflow detection) is exact.
__device__ __forceinline__ void stage_candidate(
    bool inwin, float v, uint32_t pix, float diff, int lane,
    uint32_t* ccount, uint32_t* bvb, uint32_t* bvi, uint32_t* bvd)
{
    unsigned long long m = __ballot(inwin);
    if (m == 0ull) return;                       // wave-uniform skip
    uint32_t cnt = (uint32_t)__popcll(m);
    int leader = (int)__builtin_ctzll(m);
    uint32_t base = 0u;
    if (lane == leader) base = atomicAdd(ccount, cnt);
    base = (uint32_t)__shfl((int)base, leader, 64);
    if (inwin) {
        uint32_t p = base + (uint32_t)__popcll(m & ((1ull << lane) - 1ull));
        if (p < CAPB) {
            bvb[p] = __float_as_uint(v);
            bvi[p] = pix;
            bvd[p] = __float_as_uint(diff);
        }
    }
}

// ---------------------------------------------------------------------------
// K1: round-4 proven config (SEGS=32, 4 pairs/thread, 2048 blocks) — round-5
// experiment showed SEGS=16/depth-8 regresses (VGPR pressure + load tail).
// Ballot staging, depth-4 preload, bucketed publish + per-bin diff sums,
// fused triple-reduce (the one safe piece of round 5).
// Block 0 zeroes out[0]. No device fences (round-1 lesson).
// ---------------------------------------------------------------------------
__global__ __launch_bounds__(256, 8) void k1_pass(
    const float4* __restrict__ sc, const float4* __restrict__ gn,
    const float2* __restrict__ tokp,
    float* __restrict__ pk1, float* __restrict__ psel, float* __restrict__ phi,
    uint32_t* __restrict__ gcc,
    uint32_t* __restrict__ cvb, uint32_t* __restrict__ cvi,
    uint32_t* __restrict__ cvd, uint32_t* __restrict__ whist,
    float* __restrict__ wdsumg,
    float* __restrict__ out)
{
    __shared__ uint32_t bvb[CAPB], bvi[CAPB], bvd[CAPB];    // staging order
    __shared__ uint32_t qvb[CAPB], qvi[CAPB], qvd[CAPB];    // bucketed order
    __shared__ uint32_t sh_wh[NWBIN], sh_pref[NWBIN], sh_cur[NWBIN];
    __shared__ float    sh_wds[NWBIN];
    __shared__ uint32_t ccount;
    const int tid  = threadIdx.x;
    const int lane = tid & 63;
    if (tid < CAPB) { qvb[tid] = 0u; qvi[tid] = 0u; qvd[tid] = 0u; }
    if (tid < NWBIN) { sh_wh[tid] = 0u; sh_cur[tid] = 0u; sh_wds[tid] = 0.f; }
    if (tid == 0) { ccount = 0u; if (blockIdx.x == 0) out[0] = 0.f; }
    __syncthreads();

    const int b   = blockIdx.x >> 5;
    const int seg = blockIdx.x & (SEGS - 1);
    const int pairbase = b * (NPIX / 2) + seg * 1024;   // 1024 pairs / block

    // ---- phase 1: issue ALL loads (static indexing -> registers) ----
    float4 S[4], G[4];
    float2 T[4];
    #pragma unroll
    for (int it = 0; it < 4; ++it) {
        int j = pairbase + it * 256 + tid;
        S[it] = sc[j];
        G[it] = gn[j];
        T[it] = tokp[j];
    }

    // ---- phase 2: compute ----
    float acc = 0.f, asel = 0.f, chi = 0.f;
    #pragma unroll
    for (int it = 0; it < 4; ++it) {
        int px0 = (seg * 1024 + it * 256 + tid) * 2;    // batch-local pixel idx
        {
            float d = (S[it].x + G[it].x) - (S[it].y + G[it].y);
            float lp, llp; bce_from_d(d, lp, llp);
            acc += llp;
            float diff = lp - llp;
            int k = vkey(T[it].x);
            bool hi = (k > WHI);
            asel += hi ? diff : 0.f;
            chi  += hi ? 1.f : 0.f;
            stage_candidate(!hi && (k >= WLO), T[it].x, (uint32_t)px0, diff,
                            lane, &ccount, bvb, bvi, bvd);
        }
        {
            float d = (S[it].z + G[it].z) - (S[it].w + G[it].w);
            float lp, llp; bce_from_d(d, lp, llp);
            acc += llp;
            float diff = lp - llp;
            int k = vkey(T[it].y);
            bool hi = (k > WHI);
            asel += hi ? diff : 0.f;
            chi  += hi ? 1.f : 0.f;
            stage_candidate(!hi && (k >= WLO), T[it].y, (uint32_t)(px0 + 1), diff,
                            lane, &ccount, bvb, bvi, bvd);
        }
    }
    __syncthreads();
    const uint32_t cc  = ccount;
    const uint32_t nsl = cc < CAPB ? cc : CAPB;
    // bin histogram over stored slots (~104 LDS atomics)
    if (tid < nsl) {
        int k = vkey(__uint_as_float(bvb[tid]));
        atomicAdd(&sh_wh[k - WLO], 1u);
    }
    __syncthreads();
    // exclusive prefix over 13 bins (serial, trivial)
    if (tid == 0) {
        uint32_t run = 0;
        #pragma unroll
        for (int i = 0; i < NWBIN; ++i) { sh_pref[i] = run; run += sh_wh[i]; }
    }
    __syncthreads();
    // scatter slots into bucketed order + per-bin diff sums
    if (tid < nsl) {
        uint32_t vb = bvb[tid];
        int bin = vkey(__uint_as_float(vb)) - WLO;
        uint32_t pos = sh_pref[bin] + atomicAdd(&sh_cur[bin], 1u);
        qvb[pos] = vb;
        qvi[pos] = bvi[tid];
        qvd[pos] = bvd[tid];
        atomicAdd(&sh_wds[bin], __uint_as_float(bvd[tid]));
    }
    __syncthreads();
    // publish bucketed fixed-size block (unused slots are zero sentinels)
    const size_t cbase = (size_t)blockIdx.x * CAPB;
    if (tid < CAPB) {
        cvb[cbase + tid] = qvb[tid];
        cvi[cbase + tid] = qvi[tid];
        cvd[cbase + tid] = qvd[tid];
    }
    if (tid == 0) gcc[blockIdx.x] = cc;

    float t1, t2, t3;
    block_reduce3(acc, asel, chi, &t1, &t2, &t3);
    if (tid == 0) {
        pk1[blockIdx.x]  = t1;
        psel[blockIdx.x] = t2;
        phi[blockIdx.x]  = t3;
    }
    if (tid < NWBIN) {
        whist[(size_t)blockIdx.x * WHSTRIDE + tid]  = sh_wh[tid];
        wdsumg[(size_t)blockIdx.x * WHSTRIDE + tid] = sh_wds[tid];
    }
}

// ---------------------------------------------------------------------------
// K4 (skinny): no slot walk. wc from whist; bins>sb from precomputed wdsum
// (<=384 float reads); ==sb bucket gathered via per-seg prefix offsets
// (~256 entries). Exact rank under (value desc, index asc) == lax.top_k tie
// order. Exact full-rescan fallback on any overflow (prob ~1e-10).
// ---------------------------------------------------------------------------
__global__ __launch_bounds__(1024) void k4_finalize(
    const uint32_t* __restrict__ cvb, const uint32_t* __restrict__ cvi,
    const uint32_t* __restrict__ cvd, const uint32_t* __restrict__ gcc,
    const float* __restrict__ pk1, const float* __restrict__ psel,
    const float* __restrict__ phi, const uint32_t* __restrict__ whist,
    const float* __restrict__ wdsumg,
    const float4* __restrict__ tok4,
    const float2* __restrict__ sc2, const float2* __restrict__ gn2,
    float* __restrict__ out)
{
    __shared__ uint32_t fvb[FCAP], fvi[FCAP];
    __shared__ float    fdf[FCAP];
    __shared__ uint32_t fh[NB];              // fallback histogram
    __shared__ uint32_t wc[NWBIN];
    __shared__ uint32_t segstart[SEGS], segcnt[SEGS];
    __shared__ uint32_t fcnt;
    __shared__ int      sh_sb, sh_ovf;
    __shared__ uint32_t sh_rem;

    const int b = blockIdx.x, tid = threadIdx.x;
    if (tid == 0) { fcnt = 0u; sh_sb = -1; sh_ovf = 0; sh_rem = 1u; }
    __syncthreads();

    // --- window counts from published per-block histograms (tiny) ---
    if (tid < SEGS && gcc[b * SEGS + tid] > CAPB) sh_ovf = 1;
    if (tid < NWBIN) {
        uint32_t u = 0;
        #pragma unroll
        for (int s = 0; s < SEGS; ++s)
            u += whist[(size_t)(b * SEGS + s) * WHSTRIDE + tid];
        wc[tid] = u;
    }
    float chl = (tid < SEGS) ? phi[b * SEGS + tid] : 0.f;
    float chf = block_reduce1k(chl);     // exact: integer-valued floats < 2^24
    if (tid == 0) {
        uint32_t cnt_hi = (uint32_t)(chf + 0.5f);
        if (cnt_hi >= TOPK) sh_ovf = 1;  // split bin above window
        else {
            uint32_t cum = cnt_hi;       // S[WHI+1]
            int found = -1; uint32_t rem = 1u;
            for (int jj = WHI; jj >= WLO; --jj) {
                uint32_t nc = cum + wc[jj - WLO];     // S[jj]
                if (nc >= TOPK) { found = jj; rem = TOPK - cum; break; }
                cum = nc;
            }
            if (found < 0) sh_ovf = 1;   // split bin below window
            else { sh_sb = found; sh_rem = rem; }
        }
    }
    __syncthreads();

    bool fast = (sh_ovf == 0);
    const int sb  = sh_sb;
    const int sbi = sb - WLO;
    float fac = (tid < SEGS) ? pk1[b * SEGS + tid] : 0.f;   // base llp

    if (fast) {
        if (tid < SEGS) fac += psel[b * SEGS + tid];        // key > WHI diffs
        // bins > sb: precomputed per-block diff sums (<=384 reads)
        if (tid < SEGS * WHSTRIDE) {
            int s = tid >> 4, bin = tid & 15;
            if (bin < NWBIN && bin > sbi)
                fac += wdsumg[(size_t)(b * SEGS + s) * WHSTRIDE + bin];
        }
        // per-seg offset of the ==sb bucket (prefix of seg's whist row)
        if (tid < SEGS) {
            uint32_t st = 0;
            for (int i = 0; i < sbi; ++i)
                st += whist[(size_t)(b * SEGS + tid) * WHSTRIDE + i];
            segstart[tid] = st;
            segcnt[tid]   = whist[(size_t)(b * SEGS + tid) * WHSTRIDE + sbi];
        }
        __syncthreads();
        // gather ==sb bucket entries (~256 total); 32-thread group per seg
        {
            int g = tid >> 5, l32 = tid & 31;
            uint32_t c = segcnt[g];
            size_t sbase = (size_t)(b * SEGS + g) * CAPB + segstart[g];
            for (uint32_t i = l32; i < c; i += 32) {
                uint32_t p = atomicAdd(&fcnt, 1u);
                if (p < FCAP) {
                    fvb[p] = cvb[sbase + i];
                    fvi[p] = cvi[sbase + i] & (NPIX - 1);
                    fdf[p] = __uint_as_float(cvd[sbase + i]);
                }
            }
        }
        __syncthreads();
        if (fcnt > FCAP) fast = false;   // uniform decision (shared value)
        if (fast) {
            const uint32_t cnt = fcnt, rem = sh_rem;
            for (uint32_t j = tid; j < cnt; j += 1024) {
                const uint32_t mb = fvb[j], mi = fvi[j];
                uint32_t rank = 0;
                for (uint32_t i = 0; i < cnt; ++i) {
                    uint32_t ob = fvb[i];
                    rank += (ob > mb) || (ob == mb && fvi[i] < mi);
                }
                if (rank < rem) fac += fdf[j];
            }
        }
    }

    if (!fast) {
        // ---- exact fallback: full per-batch recount + recompute ----
        fac = (tid < SEGS) ? pk1[b * SEGS + tid] : 0.f;     // reset to base
        for (int i = tid; i < NB; i += 1024) fh[i] = 0u;
        if (tid == 0) fcnt = 0u;
        __syncthreads();
        const float4* tbase = tok4 + (size_t)b * (NPIX / 4);
        for (int it = 0; it < NPIX / 4 / 1024; ++it) {
            float4 v = tbase[it * 1024 + tid];
            atomicAdd(&fh[vkey(v.x)], 1u);
            atomicAdd(&fh[vkey(v.y)], 1u);
            atomicAdd(&fh[vkey(v.z)], 1u);
            atomicAdd(&fh[vkey(v.w)], 1u);
        }
        __syncthreads();
        if (tid == 0) {
            uint32_t cum = 0; int bin = NB - 1;
            for (; bin > 0; --bin) {
                if (cum + fh[bin] >= TOPK) break;
                cum += fh[bin];
            }
            sh_sb = bin; sh_rem = TOPK - cum;
        }
        __syncthreads();
        const int sb2 = sh_sb; const uint32_t rem2 = sh_rem;
        for (int it = 0; it < NPIX / 4 / 1024; ++it) {
            int j = it * 1024 + tid;
            float4 v = tbase[j];
            int px = j * 4;
            float fv[4] = {v.x, v.y, v.z, v.w};
            #pragma unroll
            for (int q = 0; q < 4; ++q) {
                int k = vkey(fv[q]);
                if (k > sb2) {
                    size_t idx = (size_t)b * NPIX + (px + q);
                    float2 Sv = sc2[idx]; float2 Gv = gn2[idx];
                    float d = (Sv.x + Gv.x) - (Sv.y + Gv.y);
                    float lp, llp; bce_from_d(d, lp, llp);
                    fac += lp - llp;
                } else if (k == sb2) {
                    uint32_t p = atomicAdd(&fcnt, 1u);
                    if (p < FCAP) { fvb[p] = __float_as_uint(fv[q]); fvi[p] = (uint32_t)(px + q); }
                }
            }
        }
        __syncthreads();
        const uint32_t cnt2 = min(fcnt, (uint32_t)FCAP);
        for (uint32_t j = tid; j < cnt2; j += 1024) {
            const uint32_t mb = fvb[j], mi = fvi[j];
            uint32_t rank = 0;
            for (uint32_t i = 0; i < cnt2; ++i) {
                uint32_t ob = fvb[i];
                rank += (ob > mb) || (ob == mb && fvi[i] < mi);
            }
            if (rank < rem2) {
                size_t idx = (size_t)b * NPIX + (mi & (NPIX - 1));
                float2 Sv = sc2[idx]; float2 Gv = gn2[idx];
                float d = (Sv.x + Gv.x) - (Sv.y + Gv.y);
                float lp, llp; bce_from_d(d, lp, llp);
                fac += lp - llp;
            }
        }
    }

    float tot = block_reduce1k(fac);
    if (tid == 0) atomicAdd(out, -tot);   // 64 adds, out zeroed by k1
}

extern "C" void kernel_launch(void* const* d_in, const int* in_sizes, int n_in,
                              void* d_out, int out_size, void* d_ws, size_t ws_size,
                              hipStream_t stream) {
    const float* scores = (const float*)d_in[0];   // [B, N, 2]
    const float* smap   = (const float*)d_in[1];   // [B, N]
    const float* gumbel = (const float*)d_in[2];   // [B, N, 2]
    float* out = (float*)d_out;

    // workspace: every region fully written before read -> NO memset needed
    char* ws = (char*)d_ws;
    float*    pk1   = (float*)ws;    ws += (size_t)BATCH * SEGS * 4;            // 8KB
    float*    psel  = (float*)ws;    ws += (size_t)BATCH * SEGS * 4;            // 8KB
    float*    phi   = (float*)ws;    ws += (size_t)BATCH * SEGS * 4;            // 8KB
    uint32_t* gcc   = (uint32_t*)ws; ws += (size_t)BATCH * SEGS * 4;            // 8KB
    uint32_t* cvb   = (uint32_t*)ws; ws += (size_t)BATCH * NSLOT * 4;           // 1.5MB
    uint32_t* cvi   = (uint32_t*)ws; ws += (size_t)BATCH * NSLOT * 4;           // 1.5MB
    uint32_t* cvd   = (uint32_t*)ws; ws += (size_t)BATCH * NSLOT * 4;           // 1.5MB
    uint32_t* whist = (uint32_t*)ws; ws += (size_t)BATCH * SEGS * WHSTRIDE * 4; // 128KB
    float*    wdsum = (float*)ws;    ws += (size_t)BATCH * SEGS * WHSTRIDE * 4; // 128KB

    k1_pass<<<BATCH * SEGS, 256, 0, stream>>>(
        (const float4*)scores, (const float4*)gumbel, (const float2*)smap,
        pk1, psel, phi, gcc, cvb, cvi, cvd, whist, wdsum, out);

    k4_finalize<<<BATCH, 1024, 0, stream>>>(
        cvb, cvi, cvd, gcc, pk1, psel, phi, whist, wdsum,
        (const float4*)smap, (const float2*)scores, (const float2*)gumbel, out);
}